// Round 5
// baseline (395.225 us; speedup 1.0000x reference)
//
#include <hip/hip_runtime.h>
#include <math.h>
#include <stdint.h>

#define NA 32          // N_AGENTS
#define SD 2048        // STATE_DIM
#define EB 64          // EMBED
#define BT 2048        // B = BS*T
#define NCAT 2240      // 2048 (Ww1) + 64 (Wwf) + 64 (Wb1) + 64 (Wv1)
#define NPAD 2304      // padded
#define YS   2304      // Y row stride (fp32)

typedef float floatx4 __attribute__((ext_vector_type(4)));
typedef short bf16x8  __attribute__((ext_vector_type(8)));

__device__ __forceinline__ unsigned short f2bf(float f) {
    union { float f; uint32_t u; } v; v.f = f;
    uint32_t r = v.u + 0x7FFFu + ((v.u >> 16) & 1u);
    return (unsigned short)(r >> 16);
}

__device__ __forceinline__ void gload_lds16(const void* g, void* l) {
    __builtin_amdgcn_global_load_lds(
        (const __attribute__((address_space(1))) uint32_t*)g,
        (__attribute__((address_space(3))) uint32_t*)l, 16, 0, 0);
}

// ---------------- K0a: st -> bf16 row-major ----------------
__global__ __launch_bounds__(256) void k0_st2bf(const float* __restrict__ st,
                                                unsigned short* __restrict__ stb) {
    int idx = (blockIdx.x * 256 + threadIdx.x) * 4;
    float4 v = *(const float4*)(st + idx);
    ushort4 o;
    o.x = f2bf(v.x); o.y = f2bf(v.y); o.z = f2bf(v.z); o.w = f2bf(v.w);
    *(ushort4*)(stb + idx) = o;
}

// ---------------- K0b: Wt[n][k] bf16 (transposed concat, padded) ----------
__global__ __launch_bounds__(256) void k0_wt(const float* __restrict__ Ww1,
                                             const float* __restrict__ Wwf,
                                             const float* __restrict__ Wb1,
                                             const float* __restrict__ Wv1,
                                             unsigned short* __restrict__ Wtb) {
    __shared__ float tile[32][33];
    const int n0 = blockIdx.x * 32;   // 72 tiles (incl. pad)
    const int k0 = blockIdx.y * 32;   // 64 tiles
    const float* src; int ld = 64, nb = 0;
    if (n0 < 2048)      { src = Ww1; ld = 2048; nb = n0; }
    else if (n0 < 2112) { src = Wwf; nb = n0 - 2048; }
    else if (n0 < 2176) { src = Wb1; nb = n0 - 2112; }
    else if (n0 < 2240) { src = Wv1; nb = n0 - 2176; }
    else                { src = nullptr; }
    const int t = threadIdx.x;
    {
        int nl = t & 31, kl0 = t >> 5;
        #pragma unroll
        for (int r = 0; r < 4; r++) {
            int kl = kl0 + r * 8;
            tile[kl][nl] = src ? src[(size_t)(k0 + kl) * ld + nb + nl] : 0.f;
        }
    }
    __syncthreads();
    {
        int kl = t & 31, nl0 = t >> 5;
        #pragma unroll
        for (int r = 0; r < 4; r++) {
            int nl = nl0 + r * 8;
            Wtb[(size_t)(n0 + nl) * SD + k0 + kl] = f2bf(tile[kl][nl]);
        }
    }
}

// ---------------- K0c: concat bias (padded) ----------------
__global__ void k0_bias(const float* __restrict__ bw1, const float* __restrict__ bwf,
                        const float* __restrict__ bb1, const float* __restrict__ bv1,
                        float* __restrict__ bcat) {
    int n = blockIdx.x * 256 + threadIdx.x;
    if (n >= NPAD) return;
    float v = 0.f;
    if (n < 2048)      v = bw1[n];
    else if (n < 2112) v = bwf[n - 2048];
    else if (n < 2176) v = bb1[n - 2112];
    else if (n < 2240) v = bv1[n - 2176];
    bcat[n] = v;
}

// ---------------- K1: Y = st @ Wcat + bias  (bf16 MFMA) ----------------
// tile M64 x N128, 4 waves (2m x 2n), K-step 32, global_load_lds staging.
// (identical to the round-3 version that passed)
__global__ __launch_bounds__(256) void k1_gemm(const unsigned short* __restrict__ stb,
                                               const unsigned short* __restrict__ Wtb,
                                               const float* __restrict__ bcat,
                                               float* __restrict__ Y)
{
    __shared__ short As[4 * 64 * 8];    // [kg][m 0..63][8k]
    __shared__ short Bs[4 * 128 * 8];   // [kg][n 0..127][8k]
    const int t = threadIdx.x;
    const int n0 = blockIdx.x * 128;
    const int m0 = blockIdx.y * 64;
    const int wid = t >> 6, lane = t & 63;
    const int wm = wid & 1, wn = wid >> 1;
    const int quad = lane >> 4, l16 = lane & 15;

    floatx4 acc[2][4];
    #pragma unroll
    for (int i = 0; i < 2; i++)
        #pragma unroll
        for (int j = 0; j < 4; j++) acc[i][j] = (floatx4)0.f;

    for (int kt = 0; kt < SD; kt += 32) {
        gload_lds16(stb + (size_t)(m0 + (t & 63)) * SD + kt + (t >> 6) * 8, (char*)As + t * 16);
        {
            int c = t;
            gload_lds16(Wtb + (size_t)(n0 + (c & 127)) * SD + kt + (c >> 7) * 8, (char*)Bs + c * 16);
            c = t + 256;
            gload_lds16(Wtb + (size_t)(n0 + (c & 127)) * SD + kt + (c >> 7) * 8, (char*)Bs + c * 16);
        }
        __syncthreads();
        bf16x8 a[2], b[4];
        #pragma unroll
        for (int mf = 0; mf < 2; mf++)
            a[mf] = *(const bf16x8*)(As + (quad * 64 + wm * 32 + mf * 16 + l16) * 8);
        #pragma unroll
        for (int nf = 0; nf < 4; nf++)
            b[nf] = *(const bf16x8*)(Bs + (quad * 128 + wn * 64 + nf * 16 + l16) * 8);
        #pragma unroll
        for (int mf = 0; mf < 2; mf++)
            #pragma unroll
            for (int nf = 0; nf < 4; nf++)
                acc[mf][nf] = __builtin_amdgcn_mfma_f32_16x16x32_bf16(a[mf], b[nf], acc[mf][nf], 0, 0, 0);
        __syncthreads();
    }

    #pragma unroll
    for (int mf = 0; mf < 2; mf++)
        #pragma unroll
        for (int nf = 0; nf < 4; nf++) {
            int col = n0 + wn * 64 + nf * 16 + l16;
            float bias = bcat[col];
            #pragma unroll
            for (int r = 0; r < 4; r++) {
                int row = m0 + wm * 32 + mf * 16 + quad * 4 + r;
                Y[(size_t)row * YS + col] = acc[mf][nf][r] + bias;
            }
        }
}

// ---------------- K3: q1[i][b]  (4-wave blocks, agents split by wave) ----
// block = (mask i, 16-row b tile), 256 threads. Wave w handles agents
// a = w*8 .. w*8+7. Same load patterns as the passing round-3 kernel
// (scalar Y reads, Wtb [n][k] reads); hid reduced across waves via LDS.
__global__ __launch_bounds__(256) void k3_q1(
    const unsigned short* __restrict__ stb, const float* __restrict__ qs,
    const unsigned short* __restrict__ Wtb, const float* __restrict__ Wv2,
    const float* __restrict__ bv2, const float* __restrict__ Y,
    float* __restrict__ q1)
{
    const int i  = blockIdx.x;        // mask 0..31
    const int b0 = blockIdx.y * 16;   // b tile
    __shared__ short sA[16 * 64];      // [kg 0..7][m 0..15][8k]  (2 KB)
    __shared__ float qs_s[16][33];     // (2.1 KB)
    __shared__ float hidp[4][16][64];  // per-wave hid partials (16 KB)
    __shared__ float wf_lds[16][64], b1_lds[16][64], v_lds[16][64]; // (12 KB)

    const int t = threadIdx.x, w = t >> 6, lane = t & 63;
    const int quad = lane >> 4, l16 = lane & 15;

    if (t < 128) {   // 128 chunks of 16B: chunk c -> (kg = c>>4, m = c&15)
        int c = t;
        gload_lds16(stb + (size_t)(b0 + (c & 15)) * SD + i * 64 + (c >> 4) * 8,
                    (char*)sA + c * 16);
    }
    {
        int l = t * 2;
        float2 v = *(const float2*)&qs[(size_t)(b0 + (l >> 5)) * NA + (l & 31)];
        qs_s[l >> 5][(l & 31) + 0] = v.x;
        qs_s[l >> 5][(l & 31) + 1] = v.y;
    }
    __syncthreads();

    bf16x8 A0 = *(const bf16x8*)(sA + ((0 * 4 + quad) * 16 + l16) * 8);
    bf16x8 A1 = *(const bf16x8*)(sA + ((1 * 4 + quad) * 16 + l16) * 8);

    floatx4 hid[4];
    #pragma unroll
    for (int nf = 0; nf < 4; nf++) hid[nf] = (floatx4)0.f;

    const float* Yb = Y + (size_t)b0 * YS;

    for (int ia = 0; ia < 8; ia++) {              // agent a = w*8 + ia
        const int a  = w * 8 + ia;
        const int j0 = a * 64;
        floatx4 acc[4];
        #pragma unroll
        for (int nf = 0; nf < 4; nf++) {
            const float* yp = Yb + j0 + nf * 16 + l16;
            #pragma unroll
            for (int r = 0; r < 4; r++)
                acc[nf][r] = -yp[(size_t)(quad * 4 + r) * YS];
        }
        #pragma unroll
        for (int nf = 0; nf < 4; nf++) {
            const unsigned short* wp = Wtb + (size_t)(j0 + nf * 16 + l16) * SD + i * 64 + quad * 8;
            bf16x8 bb0 = *(const bf16x8*)(wp);
            bf16x8 bb1 = *(const bf16x8*)(wp + 32);
            acc[nf] = __builtin_amdgcn_mfma_f32_16x16x32_bf16(A0, bb0, acc[nf], 0, 0, 0);
            acc[nf] = __builtin_amdgcn_mfma_f32_16x16x32_bf16(A1, bb1, acc[nf], 0, 0, 0);
        }
        float qv[4];
        #pragma unroll
        for (int r = 0; r < 4; r++) qv[r] = qs_s[quad * 4 + r][a];
        #pragma unroll
        for (int nf = 0; nf < 4; nf++)
            #pragma unroll
            for (int r = 0; r < 4; r++)
                hid[nf][r] += qv[r] * fabsf(acc[nf][r]);
    }

    // write hid partials
    #pragma unroll
    for (int nf = 0; nf < 4; nf++)
        #pragma unroll
        for (int r = 0; r < 4; r++)
            hidp[w][quad * 4 + r][nf * 16 + l16] = hid[nf][r];

    // tail: frags 0..11 (wf:0-3 | b1:4-7 | v:8-11), 3 per wave
    #pragma unroll
    for (int fi = 0; fi < 3; fi++) {
        const int nft = w * 3 + fi;
        const int c0 = 2048 + nft * 16;
        floatx4 c;
        #pragma unroll
        for (int r = 0; r < 4; r++)
            c[r] = -Yb[(size_t)(quad * 4 + r) * YS + c0 + l16];
        const unsigned short* wp = Wtb + (size_t)(c0 + l16) * SD + i * 64 + quad * 8;
        c = __builtin_amdgcn_mfma_f32_16x16x32_bf16(A0, *(const bf16x8*)(wp), c, 0, 0, 0);
        c = __builtin_amdgcn_mfma_f32_16x16x32_bf16(A1, *(const bf16x8*)(wp + 32), c, 0, 0, 0);
        const int e = (nft & 3) * 16 + l16;
        #pragma unroll
        for (int r = 0; r < 4; r++) {
            int b = quad * 4 + r;
            float cv = c[r];
            if (nft < 4)      wf_lds[b][e] = fabsf(cv);
            else if (nft < 8) b1_lds[b][e] = -cv;
            else              v_lds[b][e]  = fmaxf(-cv, 0.f) * Wv2[e];
        }
    }
    __syncthreads();

    // final: hidden = elu(sum_w hidp + b1); q1 = sum_e(hidden*wf + v) + bv2
    const float bv2v = bv2[0];
    #pragma unroll
    for (int bb = 0; bb < 4; bb++) {
        int b = w * 4 + bb;
        float hid_tot = hidp[0][b][lane] + hidp[1][b][lane]
                      + hidp[2][b][lane] + hidp[3][b][lane];
        float h = hid_tot + b1_lds[b][lane];
        h = h > 0.f ? h : expm1f(h);
        float val = h * wf_lds[b][lane] + v_lds[b][lane];
        #pragma unroll
        for (int off = 32; off > 0; off >>= 1) val += __shfl_xor(val, off);
        if (lane == 0) q1[(size_t)i * BT + b0 + b] = val + bv2v;
    }
}

// ---------------- K4: q_tot, wc, final weighted mix ----------------
__global__ __launch_bounds__(64) void k4_final(
    const float* __restrict__ qs, const float* __restrict__ Y,
    const float* __restrict__ q1, const float* __restrict__ Wv2,
    const float* __restrict__ bv2, float* __restrict__ out)
{
    const int b = blockIdx.x;
    const int e = threadIdx.x;   // 0..63
    const float* yrow = &Y[(size_t)b * YS];

    float w1r[32];
    #pragma unroll
    for (int a = 0; a < 32; a++) w1r[a] = fabsf(yrow[a * 64 + e]);
    float wf   = fabsf(yrow[2048 + e]);
    float b1   = yrow[2112 + e];
    float vpre = fmaxf(yrow[2176 + e], 0.f) * Wv2[e];
    const float bv2v = bv2[0];

    __shared__ float qs_s[32];
    __shared__ float qw[32];
    if (e < 32) qs_s[e] = qs[(size_t)b * NA + e];
    __syncthreads();

    float hl = 0.f;
    #pragma unroll
    for (int a = 0; a < 32; a++) hl += qs_s[a] * w1r[a];
    float hid = hl + b1; hid = hid > 0.f ? hid : expm1f(hid);
    float val = hid * wf + vpre;
    #pragma unroll
    for (int off = 32; off > 0; off >>= 1) val += __shfl_down(val, off);
    float q_tot = __shfl(val, 0) + bv2v;

    if (e < 32) {
        float d = fabsf(q_tot - q1[(size_t)e * BT + b]);
        float ss = d * d;
        #pragma unroll
        for (int off = 16; off > 0; off >>= 1) ss += __shfl_xor(ss, off, 32);
        float nrm = fmaxf(sqrtf(ss), 1e-12f);
        qw[e] = qs_s[e] * (d / nrm);
    }
    __syncthreads();

    float hl2 = 0.f;
    #pragma unroll
    for (int a = 0; a < 32; a++) hl2 += qw[a] * w1r[a];
    float hid2 = hl2 + b1; hid2 = hid2 > 0.f ? hid2 : expm1f(hid2);
    float val2 = hid2 * wf + vpre;
    #pragma unroll
    for (int off = 32; off > 0; off >>= 1) val2 += __shfl_down(val2, off);
    if (e == 0) out[b] = val2 + bv2v;
}

extern "C" void kernel_launch(void* const* d_in, const int* in_sizes, int n_in,
                              void* d_out, int out_size, void* d_ws, size_t ws_size,
                              hipStream_t stream) {
    const float* qs  = (const float*)d_in[0];
    const float* st  = (const float*)d_in[1];
    const float* Ww1 = (const float*)d_in[2];
    const float* bw1 = (const float*)d_in[3];
    const float* Wwf = (const float*)d_in[4];
    const float* bwf = (const float*)d_in[5];
    const float* Wb1 = (const float*)d_in[6];
    const float* bb1 = (const float*)d_in[7];
    const float* Wv1 = (const float*)d_in[8];
    const float* bv1 = (const float*)d_in[9];
    const float* Wv2 = (const float*)d_in[10];
    const float* bv2 = (const float*)d_in[11];
    float* out = (float*)d_out;

    // workspace layout (~37 MB)
    float* Y            = (float*)d_ws;                           // 2048*2304 f32
    unsigned short* stb = (unsigned short*)(Y + (size_t)BT * YS); // 2048*2048 bf16
    unsigned short* Wtb = stb + (size_t)SD * SD;                  // 2304*2048 bf16
    float* bcat         = (float*)(Wtb + (size_t)NPAD * SD);      // 2304 f32
    float* q1v          = bcat + NPAD;                            // 32*2048 f32

    k0_st2bf<<<(SD * SD / 4 + 255) / 256, 256, 0, stream>>>(st, stb);
    k0_wt  <<<dim3(NPAD / 32, SD / 32), 256, 0, stream>>>(Ww1, Wwf, Wb1, Wv1, Wtb);
    k0_bias<<<(NPAD + 255) / 256, 256, 0, stream>>>(bw1, bwf, bb1, bv1, bcat);

    k1_gemm<<<dim3(NPAD / 128, BT / 64), 256, 0, stream>>>(stb, Wtb, bcat, Y);
    k3_q1  <<<dim3(NA, BT / 16), 256, 0, stream>>>(stb, qs, Wtb, Wv2, bv2, Y, q1v);
    k4_final<<<BT, 64, 0, stream>>>(qs, Y, q1v, Wv2, bv2, out);
}

// Round 6
// 217.900 us; speedup vs baseline: 1.8138x; 1.8138x over previous
//
#include <hip/hip_runtime.h>
#include <math.h>
#include <stdint.h>

#define NA 32          // N_AGENTS
#define SD 2048        // STATE_DIM
#define BT 2048        // B = BS*T
#define NFRG 144       // col frags (2304 padded cols / 16); 128 agent + 12 tail + 4 pad

typedef float floatx4 __attribute__((ext_vector_type(4)));
typedef short bf16x8  __attribute__((ext_vector_type(8)));

__device__ __forceinline__ unsigned short f2bf(float f) {
    union { float f; uint32_t u; } v; v.f = f;
    uint32_t r = v.u + 0x7FFFu + ((v.u >> 16) & 1u);
    return (unsigned short)(r >> 16);
}

// ---- fragment layouts ----
// A-frag (stA):  elem((bt*64+kc)*512 + (quad*16+l16)*8 + j) = st[bt*16+l16][kc*32+quad*8+j]
// B-frag (Wswz): elem(((i*NFRG+f)*2+h)*512 + (quad*16+l16)*8 + j) = W[n=f*16+l16][k=i*64+h*32+quad*8+j]
// C-frag (Ycn):  elem((bt*NFRG+f)*256 + (quad*16+l16)*4 + r) = -Y[bt*16+quad*4+r][f*16+l16]

// ---------------- K0a: st -> A-fragment-order bf16 ----------------
__global__ __launch_bounds__(256) void k0_ast(const float* __restrict__ st,
                                              unsigned short* __restrict__ stA) {
    int idx = blockIdx.x * 256 + threadIdx.x;   // 2048*256 threads
    int m = idx >> 8, kg = idx & 255;           // kg = 8-elem group along k
    int k0 = kg * 8;
    const float* src = st + (size_t)m * SD + k0;
    float4 v0 = *(const float4*)src;
    float4 v1 = *(const float4*)(src + 4);
    int bt = m >> 4, l16 = m & 15, kc = kg >> 2, quad = kg & 3;
    unsigned short* dst = stA + ((size_t)bt * 64 + kc) * 512 + (quad * 16 + l16) * 8;
    ushort4 o0, o1;
    o0.x = f2bf(v0.x); o0.y = f2bf(v0.y); o0.z = f2bf(v0.z); o0.w = f2bf(v0.w);
    o1.x = f2bf(v1.x); o1.y = f2bf(v1.y); o1.z = f2bf(v1.z); o1.w = f2bf(v1.w);
    *(ushort4*)(dst)     = o0;
    *(ushort4*)(dst + 4) = o1;
}

// ---------------- K0b: weights -> B-fragment-order bf16 ----------------
__global__ __launch_bounds__(256) void k0_wswz(const float* __restrict__ Ww1,
                                               const float* __restrict__ Wwf,
                                               const float* __restrict__ Wb1,
                                               const float* __restrict__ Wv1,
                                               unsigned short* __restrict__ Wswz) {
    __shared__ float tile[32][33];
    const int n0 = blockIdx.x * 32;   // 72 tiles
    const int k0 = blockIdx.y * 32;   // 64 tiles
    const float* src; int ld = 64, nb = 0;
    if (n0 < 2048)      { src = Ww1; ld = 2048; nb = n0; }
    else if (n0 < 2112) { src = Wwf; nb = n0 - 2048; }
    else if (n0 < 2176) { src = Wb1; nb = n0 - 2112; }
    else if (n0 < 2240) { src = Wv1; nb = n0 - 2176; }
    else                { src = nullptr; }
    const int t = threadIdx.x;
    {
        int nl = t & 31, kl0 = t >> 5;
        #pragma unroll
        for (int r = 0; r < 4; r++) {
            int kl = kl0 + r * 8;
            tile[kl][nl] = src ? src[(size_t)(k0 + kl) * ld + nb + nl] : 0.f;
        }
    }
    __syncthreads();
    {
        int kl = t & 31, nl0 = t >> 5;
        #pragma unroll
        for (int r = 0; r < 4; r++) {
            int nl = nl0 + r * 8;
            int n = n0 + nl, k = k0 + kl;
            int f = n >> 4, l16 = n & 15;
            int i = k >> 6, kr = k & 63;
            int h = kr >> 5, quad = (kr & 31) >> 3, j = kr & 7;
            size_t off = (((size_t)i * NFRG + f) * 2 + h) * 512 + (quad * 16 + l16) * 8 + j;
            Wswz[off] = f2bf(tile[kl][nl]);
        }
    }
}

// ---------------- K0c: concat bias (padded) ----------------
__global__ void k0_bias(const float* __restrict__ bw1, const float* __restrict__ bwf,
                        const float* __restrict__ bb1, const float* __restrict__ bv1,
                        float* __restrict__ bcat) {
    int n = blockIdx.x * 256 + threadIdx.x;
    if (n >= NFRG * 16) return;
    float v = 0.f;
    if (n < 2048)      v = bw1[n];
    else if (n < 2112) v = bwf[n - 2048];
    else if (n < 2176) v = bb1[n - 2112];
    else if (n < 2240) v = bv1[n - 2176];
    bcat[n] = v;
}

// ---------------- K1: Ycn = -(st @ Wcat + bias), fragment layout ----------
// No LDS, no barriers: all operands register-streamed from fragment-order
// buffers. 4 waves: wm = wid&1 (m half), wn = wid>>1 (n half).
__global__ __launch_bounds__(256) void k1_gemm(const unsigned short* __restrict__ stA,
                                               const unsigned short* __restrict__ Wswz,
                                               const float* __restrict__ bcat,
                                               float* __restrict__ Ycn)
{
    const int t = threadIdx.x;
    const int m0t = blockIdx.x * 4;   // btile base (64 rows)
    const int n0f = blockIdx.y * 8;   // frag base (128 cols)
    const int wid = t >> 6, lane = t & 63;
    const int wm = wid & 1, wn = wid >> 1;
    const int l16 = lane & 15;

    floatx4 acc[2][4];
    #pragma unroll
    for (int i = 0; i < 2; i++)
        #pragma unroll
        for (int j = 0; j < 4; j++) acc[i][j] = (floatx4)0.f;

    const unsigned short* Ap0 = stA + ((size_t)(m0t + wm * 2 + 0) * 64) * 512 + lane * 8;
    const unsigned short* Ap1 = stA + ((size_t)(m0t + wm * 2 + 1) * 64) * 512 + lane * 8;

    #pragma unroll 2
    for (int kc = 0; kc < 64; kc++) {           // K-step 32
        bf16x8 a0 = *(const bf16x8*)(Ap0 + (size_t)kc * 512);
        bf16x8 a1 = *(const bf16x8*)(Ap1 + (size_t)kc * 512);
        const int i = kc >> 1, h = kc & 1;
        const unsigned short* Bp =
            Wswz + (((size_t)i * NFRG + n0f + wn * 4) * 2 + h) * 512 + lane * 8;
        #pragma unroll
        for (int nf = 0; nf < 4; nf++) {
            bf16x8 b = *(const bf16x8*)(Bp + (size_t)nf * 1024);
            acc[0][nf] = __builtin_amdgcn_mfma_f32_16x16x32_bf16(a0, b, acc[0][nf], 0, 0, 0);
            acc[1][nf] = __builtin_amdgcn_mfma_f32_16x16x32_bf16(a1, b, acc[1][nf], 0, 0, 0);
        }
    }

    #pragma unroll
    for (int mf = 0; mf < 2; mf++)
        #pragma unroll
        for (int nf = 0; nf < 4; nf++) {
            const int f  = n0f + wn * 4 + nf;
            const int bt = m0t + wm * 2 + mf;
            const float bias = bcat[f * 16 + l16];
            floatx4 o;
            #pragma unroll
            for (int r = 0; r < 4; r++) o[r] = -(acc[mf][nf][r] + bias);
            *(floatx4*)(Ycn + ((size_t)bt * NFRG + f) * 256 + lane * 4) = o;
        }
}

// ---------------- K3: q1[i][b], single wave, all-contiguous loads --------
// C-init from Ycn (= -Y) so after MFMA: c = P - Y = -D.
__global__ __launch_bounds__(64) void k3_q1(
    const unsigned short* __restrict__ stA, const float* __restrict__ qs,
    const unsigned short* __restrict__ Wswz, const float* __restrict__ Wv2,
    const float* __restrict__ bv2, const float* __restrict__ Ycn,
    float* __restrict__ q1)
{
    const int bt = blockIdx.x;        // b tile 0..127
    const int i  = blockIdx.y;        // mask 0..31
    __shared__ float qs_s[16][33];

    const int t = threadIdx.x;        // == lane
    const int quad = t >> 4, l16 = t & 15;

    {
        int b = t >> 2, a0 = (t & 3) * 8;
        const float* src = qs + (size_t)(bt * 16 + b) * NA + a0;
        #pragma unroll
        for (int u = 0; u < 8; u++) qs_s[b][a0 + u] = src[u];
    }
    bf16x8 A0 = *(const bf16x8*)(stA + ((size_t)bt * 64 + 2 * i + 0) * 512 + t * 8);
    bf16x8 A1 = *(const bf16x8*)(stA + ((size_t)bt * 64 + 2 * i + 1) * 512 + t * 8);
    __syncthreads();

    floatx4 hid[4];
    #pragma unroll
    for (int nf = 0; nf < 4; nf++) hid[nf] = (floatx4)0.f;

    const float*          Yb = Ycn  + (size_t)bt * NFRG * 256;
    const unsigned short* Wb = Wswz + (size_t)i * NFRG * 1024;

    for (int a = 0; a < 32; a++) {
        const float*          yp = Yb + (size_t)(a * 4) * 256 + t * 4;
        const unsigned short* wp = Wb + (size_t)(a * 4) * 1024 + t * 8;
        floatx4 acc[4];
        #pragma unroll
        for (int nf = 0; nf < 4; nf++) acc[nf] = *(const floatx4*)(yp + nf * 256);
        #pragma unroll
        for (int nf = 0; nf < 4; nf++) {
            bf16x8 b0 = *(const bf16x8*)(wp + nf * 1024);
            bf16x8 b1 = *(const bf16x8*)(wp + nf * 1024 + 512);
            acc[nf] = __builtin_amdgcn_mfma_f32_16x16x32_bf16(A0, b0, acc[nf], 0, 0, 0);
            acc[nf] = __builtin_amdgcn_mfma_f32_16x16x32_bf16(A1, b1, acc[nf], 0, 0, 0);
        }
        float qv[4];
        #pragma unroll
        for (int r = 0; r < 4; r++) qv[r] = qs_s[quad * 4 + r][a];
        #pragma unroll
        for (int nf = 0; nf < 4; nf++)
            #pragma unroll
            for (int r = 0; r < 4; r++)
                hid[nf][r] += qv[r] * fabsf(acc[nf][r]);
    }

    // tail frags 128..139: wf(0-3) | b1(4-7) | v(8-11)
    floatx4 wff[4], b1f[4], vacc = (floatx4)0.f;
    #pragma unroll
    for (int nft = 0; nft < 12; nft++) {
        const int f = 128 + nft;
        floatx4 c = *(const floatx4*)(Yb + (size_t)f * 256 + t * 4);
        const unsigned short* wp = Wb + (size_t)f * 1024 + t * 8;
        c = __builtin_amdgcn_mfma_f32_16x16x32_bf16(A0, *(const bf16x8*)(wp),       c, 0, 0, 0);
        c = __builtin_amdgcn_mfma_f32_16x16x32_bf16(A1, *(const bf16x8*)(wp + 512), c, 0, 0, 0);
        if (nft < 4) {
            #pragma unroll
            for (int r = 0; r < 4; r++) wff[nft][r] = fabsf(c[r]);
        } else if (nft < 8) {
            #pragma unroll
            for (int r = 0; r < 4; r++) b1f[nft - 4][r] = -c[r];
        } else {
            float wv2 = Wv2[(nft - 8) * 16 + l16];
            #pragma unroll
            for (int r = 0; r < 4; r++) vacc[r] += fmaxf(-c[r], 0.f) * wv2;
        }
    }

    const float bv2v = bv2[0];
    #pragma unroll
    for (int r = 0; r < 4; r++) {
        float s = vacc[r];
        #pragma unroll
        for (int nf = 0; nf < 4; nf++) {
            float h = hid[nf][r] + b1f[nf][r];
            h = h > 0.f ? h : expm1f(h);
            s += h * wff[nf][r];
        }
        s += __shfl_xor(s, 1); s += __shfl_xor(s, 2);
        s += __shfl_xor(s, 4); s += __shfl_xor(s, 8);
        if (l16 == 0) q1[(size_t)i * BT + bt * 16 + quad * 4 + r] = s + bv2v;
    }
}

// ---------------- K4: q_tot, wc, final mix — fragment-layout consumer ----
// block = b-tile, 4 waves; wave w owns agents w*8..w*8+7 and 3 tail frags.
__global__ __launch_bounds__(256) void k4_final(
    const float* __restrict__ qs, const float* __restrict__ Ycn,
    const float* __restrict__ q1, const float* __restrict__ Wv2,
    const float* __restrict__ bv2, float* __restrict__ out)
{
    const int bt = blockIdx.x;
    __shared__ float qs_s[16][33];
    __shared__ float qw_s[16][33];
    __shared__ float hidp[4][16][64];
    __shared__ float wfb[16][64], b1b[16][64], vb[16][64];
    __shared__ float qt[16];

    const int t = threadIdx.x, w = t >> 6, lane = t & 63;
    const int quad = lane >> 4, l16 = lane & 15;
    const float bv2v = bv2[0];

    {
        int l = t * 2;
        float2 v = *(const float2*)&qs[(size_t)(bt * 16 + (l >> 5)) * NA + (l & 31)];
        qs_s[l >> 5][(l & 31) + 0] = v.x;
        qs_s[l >> 5][(l & 31) + 1] = v.y;
    }
    __syncthreads();

    const float* Yb = Ycn + (size_t)bt * NFRG * 256;

    // pass 1: hid with plain qs
    floatx4 hid[4];
    #pragma unroll
    for (int nf = 0; nf < 4; nf++) hid[nf] = (floatx4)0.f;
    for (int ia = 0; ia < 8; ia++) {
        const int a = w * 8 + ia;
        const float* yp = Yb + (size_t)(a * 4) * 256 + lane * 4;
        float qv[4];
        #pragma unroll
        for (int r = 0; r < 4; r++) qv[r] = qs_s[quad * 4 + r][a];
        #pragma unroll
        for (int nf = 0; nf < 4; nf++) {
            floatx4 c = *(const floatx4*)(yp + nf * 256);   // c = -Y
            #pragma unroll
            for (int r = 0; r < 4; r++) hid[nf][r] += qv[r] * fabsf(c[r]);
        }
    }
    #pragma unroll
    for (int nf = 0; nf < 4; nf++)
        #pragma unroll
        for (int r = 0; r < 4; r++)
            hidp[w][quad * 4 + r][nf * 16 + l16] = hid[nf][r];

    // tail frags: 3 per wave
    #pragma unroll
    for (int fi = 0; fi < 3; fi++) {
        const int nft = w * 3 + fi;
        floatx4 c = *(const floatx4*)(Yb + (size_t)(128 + nft) * 256 + lane * 4);
        const int e = (nft & 3) * 16 + l16;
        #pragma unroll
        for (int r = 0; r < 4; r++) {
            int b = quad * 4 + r;
            if (nft < 4)      wfb[b][e] = fabsf(c[r]);
            else if (nft < 8) b1b[b][e] = -c[r];
            else              vb[b][e]  = fmaxf(-c[r], 0.f) * Wv2[e];
        }
    }
    __syncthreads();

    // q_tot for rows w*4..w*4+3
    #pragma unroll
    for (int bb = 0; bb < 4; bb++) {
        int b = w * 4 + bb;
        float h = hidp[0][b][lane] + hidp[1][b][lane]
                + hidp[2][b][lane] + hidp[3][b][lane] + b1b[b][lane];
        h = h > 0.f ? h : expm1f(h);
        float val = h * wfb[b][lane] + vb[b][lane];
        #pragma unroll
        for (int off = 32; off > 0; off >>= 1) val += __shfl_xor(val, off);
        if (lane == 0) qt[b] = val + bv2v;
    }
    __syncthreads();

    // wc: thread (w,quad,l16) -> row rr = w*4+quad, agents 2*l16, 2*l16+1
    {
        const int rr = w * 4 + quad;
        float qtv = qt[rr];
        float d0 = fabsf(qtv - q1[(size_t)(2 * l16 + 0) * BT + bt * 16 + rr]);
        float d1 = fabsf(qtv - q1[(size_t)(2 * l16 + 1) * BT + bt * 16 + rr]);
        float ss = d0 * d0 + d1 * d1;
        ss += __shfl_xor(ss, 1); ss += __shfl_xor(ss, 2);
        ss += __shfl_xor(ss, 4); ss += __shfl_xor(ss, 8);
        float inv = 1.f / fmaxf(sqrtf(ss), 1e-12f);
        qw_s[rr][2 * l16 + 0] = qs_s[rr][2 * l16 + 0] * d0 * inv;
        qw_s[rr][2 * l16 + 1] = qs_s[rr][2 * l16 + 1] * d1 * inv;
    }
    __syncthreads();

    // pass 2: hid with qs*wc
    floatx4 hid2[4];
    #pragma unroll
    for (int nf = 0; nf < 4; nf++) hid2[nf] = (floatx4)0.f;
    for (int ia = 0; ia < 8; ia++) {
        const int a = w * 8 + ia;
        const float* yp = Yb + (size_t)(a * 4) * 256 + lane * 4;
        float qv[4];
        #pragma unroll
        for (int r = 0; r < 4; r++) qv[r] = qw_s[quad * 4 + r][a];
        #pragma unroll
        for (int nf = 0; nf < 4; nf++) {
            floatx4 c = *(const floatx4*)(yp + nf * 256);
            #pragma unroll
            for (int r = 0; r < 4; r++) hid2[nf][r] += qv[r] * fabsf(c[r]);
        }
    }
    #pragma unroll
    for (int nf = 0; nf < 4; nf++)
        #pragma unroll
        for (int r = 0; r < 4; r++)
            hidp[w][quad * 4 + r][nf * 16 + l16] = hid2[nf][r];
    __syncthreads();

    #pragma unroll
    for (int bb = 0; bb < 4; bb++) {
        int b = w * 4 + bb;
        float h = hidp[0][b][lane] + hidp[1][b][lane]
                + hidp[2][b][lane] + hidp[3][b][lane] + b1b[b][lane];
        h = h > 0.f ? h : expm1f(h);
        float val = h * wfb[b][lane] + vb[b][lane];
        #pragma unroll
        for (int off = 32; off > 0; off >>= 1) val += __shfl_xor(val, off);
        if (lane == 0) out[bt * 16 + b] = val + bv2v;
    }
}

extern "C" void kernel_launch(void* const* d_in, const int* in_sizes, int n_in,
                              void* d_out, int out_size, void* d_ws, size_t ws_size,
                              hipStream_t stream) {
    const float* qs  = (const float*)d_in[0];
    const float* st  = (const float*)d_in[1];
    const float* Ww1 = (const float*)d_in[2];
    const float* bw1 = (const float*)d_in[3];
    const float* Wwf = (const float*)d_in[4];
    const float* bwf = (const float*)d_in[5];
    const float* Wb1 = (const float*)d_in[6];
    const float* bb1 = (const float*)d_in[7];
    const float* Wv1 = (const float*)d_in[8];
    const float* bv1 = (const float*)d_in[9];
    const float* Wv2 = (const float*)d_in[10];
    const float* bv2 = (const float*)d_in[11];
    float* out = (float*)d_out;

    // workspace (~37 MB, same footprint as the proven R3/R5 layout)
    float* Ycn           = (float*)d_ws;                           // 128*144*256 f32 = 18.87 MB
    unsigned short* stA  = (unsigned short*)(Ycn + (size_t)128 * NFRG * 256); // 8.39 MB
    unsigned short* Wswz = stA + (size_t)SD * SD;                  // 32*144*1024 bf16 = 9.44 MB
    float* bcat          = (float*)(Wswz + (size_t)32 * NFRG * 1024); // 2304 f32
    float* q1v           = bcat + NFRG * 16;                       // 32*2048 f32

    k0_ast <<<(SD * SD / 8 + 255) / 256, 256, 0, stream>>>(st, stA);
    k0_wswz<<<dim3(NFRG / 2, SD / 32), 256, 0, stream>>>(Ww1, Wwf, Wb1, Wv1, Wswz);
    k0_bias<<<(NFRG * 16 + 255) / 256, 256, 0, stream>>>(bw1, bwf, bb1, bv1, bcat);

    k1_gemm<<<dim3(BT / 64, NFRG / 8), 256, 0, stream>>>(stA, Wswz, bcat, Ycn);
    k3_q1  <<<dim3(BT / 16, NA), 64, 0, stream>>>(stA, qs, Wswz, Wv2, bv2, Ycn, q1v);
    k4_final<<<BT / 16, 256, 0, stream>>>(qs, Ycn, q1v, Wv2, bv2, out);
}